// Round 4
// baseline (467.097 us; speedup 1.0000x reference)
//
#include <hip/hip_runtime.h>

// ============================================================================
// RegionNonLocalEnhancedDenseBlock on MI355X (gfx950) — Round 4
//  - kvx_kernel: x -> xt (bf16 pixel-major, vector stores) + pooled K / V^T
//    via MFMA + in-register 2x2 maxpool + LDS-staged vector stores.
//  - attn_kernel: Q computed in-kernel from xt; S/P/O/Wo MFMA chain; epilogue
//    residual from xt; ALL global accesses are 16B-per-lane vector ops.
//  - conv3x3 / fuse unchanged (bf16 MFMA implicit GEMM).
// ws overlays (ushort idx): f0@0(16.7M) f1@16.7M f2@25.2M f3@33.6M
//   xt@16.7M(16.7M, on f1+f2)  kg@33.6M(2.1M, on f3)  vt@35.7M(2.1M, on f3)
//   weights @41.9M+
// ============================================================================

typedef short s16x8 __attribute__((ext_vector_type(8)));
typedef float f32x4 __attribute__((ext_vector_type(4)));
typedef unsigned short ushort_t;

__device__ __forceinline__ unsigned short f2bf(float f) {
  union { float f; unsigned int u; } v; v.f = f;
  unsigned int r = v.u + 0x7fffu + ((v.u >> 16) & 1u);  // RNE
  return (unsigned short)(r >> 16);
}
__device__ __forceinline__ float bf2f(unsigned short h) {
  union { unsigned int u; float f; } v; v.u = ((unsigned int)h) << 16;
  return v.f;
}

// ---------------------------------------------------------------------------
// Repack conv/fuse weights -> bf16 MFMA B-frag order.
// ---------------------------------------------------------------------------
__global__ void repack_kernel(const float* __restrict__ W1, const float* __restrict__ W2,
                              const float* __restrict__ W3, const float* __restrict__ Wf,
                              ushort_t* __restrict__ wc1, ushort_t* __restrict__ wc2,
                              ushort_t* __restrict__ wc3, ushort_t* __restrict__ wff)
{
  const int i = blockIdx.x * 256 + threadIdx.x;
  if (i < 18432) {  // W1 [32][64][3][3], Kg=8
    int j = i & 7, o = (i >> 3) & 31, r = i >> 8, tap = r >> 3, kg = r & 7;
    wc1[i] = f2bf(W1[o * 576 + (kg * 8 + j) * 9 + tap]);
  }
  if (i < 27648) {  // W2 [32][96][3][3], Kg=12
    int j = i & 7, o = (i >> 3) & 31, r = i >> 8, tap = r / 12, kg = r % 12;
    wc2[i] = f2bf(W2[o * 864 + (kg * 8 + j) * 9 + tap]);
  }
  if (i < 36864) {  // W3 [32][128][3][3], Kg=16
    int j = i & 7, o = (i >> 3) & 31, r = i >> 8, tap = r >> 4, kg = r & 15;
    wc3[i] = f2bf(W3[o * 1152 + (kg * 8 + j) * 9 + tap]);
  }
  if (i < 10240) {  // Wf [64][160], Kg=20
    int j = i & 7, o = (i >> 3) & 63, kg = i >> 9;
    wff[i] = f2bf(Wf[o * 160 + kg * 8 + j]);
  }
}

// ---------------------------------------------------------------------------
// kvx_kernel: grid 2048 (8 blocks/cell, 4 waves). Wave w=0..31 of a cell:
// rows {2yp, 2yp+1}, x-half h. Emits:
//   xt[n][pix][64]  (bf16 transpose of x, vector stores from A-frags)
//   kg[cell][kpos][32]   (pooled K, bias applied)
//   vt[cell][32][kpos]   (pooled V^T, bias applied)
// ---------------------------------------------------------------------------
__global__ __launch_bounds__(256, 4) void kvx_kernel(
    const float* __restrict__ x,
    const float* __restrict__ Wk, const float* __restrict__ bk,
    const float* __restrict__ Wv, const float* __restrict__ bv,
    ushort_t* __restrict__ xt, ushort_t* __restrict__ kg, ushort_t* __restrict__ vt)
{
  __shared__ ushort_t kvs[4][8][64];  // [wave][kpos_local][K 0..31 | V 32..63]

  const int bid = blockIdx.x;
  const int cell = bid >> 3;
  const int tid = threadIdx.x, lane = tid & 63, wv = tid >> 6;
  const int w = (bid & 7) * 4 + wv;        // 0..31 within cell
  const int yp = w >> 1, h = w & 1;
  const int quad = lane >> 4, l15 = lane & 15;

  const int n  = cell >> 6;
  const int gh = (cell >> 3) & 7;
  const int gw = cell & 7;
  const int y0 = gh * 32, xc0 = gw * 32;
  const float* xn  = x  + (size_t)n * (64 * 65536);
  ushort_t*    xtn = xt + (size_t)n * (65536 * 64);

  // B-frags: W[o][c] -> B[k=c][n=o]
  s16x8 wkf[2][2], wvf[2][2];
#pragma unroll
  for (int ks = 0; ks < 2; ++ks)
#pragma unroll
    for (int nt = 0; nt < 2; ++nt) {
      const int off = (nt * 16 + l15) * 64 + ks * 32 + quad * 8;
      s16x8 tk, tv;
#pragma unroll
      for (int j = 0; j < 8; ++j) {
        tk[j] = (short)f2bf(Wk[off + j]);
        tv[j] = (short)f2bf(Wv[off + j]);
      }
      wkf[ks][nt] = tk; wvf[ks][nt] = tv;
    }
  float bkv[2], bvv[2];
#pragma unroll
  for (int nt = 0; nt < 2; ++nt) {
    bkv[nt] = bk[nt * 16 + l15];
    bvv[nt] = bv[nt * 16 + l15];
  }

  const f32x4 zf = {0.f, 0.f, 0.f, 0.f};
  f32x4 kd[2][2], vd[2][2];

#pragma unroll
  for (int t2 = 0; t2 < 2; ++t2) {
    const int yy = 2 * yp + t2;
    const int xx = h * 16 + l15;
    const float* px = xn + (y0 + yy) * 256 + xc0 + xx;

    s16x8 a[2];
#pragma unroll
    for (int ks = 0; ks < 2; ++ks)
#pragma unroll
      for (int j = 0; j < 8; ++j)
        a[ks][j] = (short)f2bf(px[(size_t)(ks * 32 + quad * 8 + j) * 65536]);

    // xt vector stores: lane holds exactly xt[pix][ks*32+quad*8 .. +7]
    const size_t pixg = (size_t)((y0 + yy) * 256 + xc0 + xx);
    *(s16x8*)(xtn + pixg * 64 + quad * 8)      = a[0];
    *(s16x8*)(xtn + pixg * 64 + 32 + quad * 8) = a[1];

#pragma unroll
    for (int nt = 0; nt < 2; ++nt) {
      kd[t2][nt] = zf; vd[t2][nt] = zf;
#pragma unroll
      for (int ks = 0; ks < 2; ++ks) {
        kd[t2][nt] = __builtin_amdgcn_mfma_f32_16x16x32_bf16(a[ks], wkf[ks][nt], kd[t2][nt], 0, 0, 0);
        vd[t2][nt] = __builtin_amdgcn_mfma_f32_16x16x32_bf16(a[ks], wvf[ks][nt], vd[t2][nt], 0, 0, 0);
      }
    }
  }

  // 2x2 maxpool: horizontal = reg pairs (2r,2r+1), vertical = t2 pair
#pragma unroll
  for (int nt = 0; nt < 2; ++nt) {
#pragma unroll
    for (int r = 0; r < 2; ++r) {
      const float kp = fmaxf(fmaxf(kd[0][nt][2 * r], kd[0][nt][2 * r + 1]),
                             fmaxf(kd[1][nt][2 * r], kd[1][nt][2 * r + 1])) + bkv[nt];
      const float vp = fmaxf(fmaxf(vd[0][nt][2 * r], vd[0][nt][2 * r + 1]),
                             fmaxf(vd[1][nt][2 * r], vd[1][nt][2 * r + 1])) + bvv[nt];
      kvs[wv][quad * 2 + r][nt * 16 + l15]      = f2bf(kp);
      kvs[wv][quad * 2 + r][32 + nt * 16 + l15] = f2bf(vp);
    }
  }
  __syncthreads();

  const int kpos0 = yp * 16 + h * 8;   // wave's 8 contiguous kpos
  if (lane < 32) {
    // K: [kpos][32ch] rows, 16B per lane
    const s16x8 vv = *(const s16x8*)&kvs[wv][lane >> 2][(lane & 3) * 8];
    *(s16x8*)(kg + ((size_t)(cell << 8) + kpos0 + (lane >> 2)) * 32 + (lane & 3) * 8) = vv;
  } else {
    // V^T: [ch][256 kpos], 8 contiguous kpos per lane
    const int ch = lane - 32;
    s16x8 vv;
#pragma unroll
    for (int r = 0; r < 8; ++r) vv[r] = (short)kvs[wv][r][32 + ch];
    *(s16x8*)(vt + (size_t)(cell << 13) + ch * 256 + kpos0) = vv;
  }
}

// ---------------------------------------------------------------------------
// attn_kernel: grid 1024 (4 blocks/cell), 4 waves, 4 M-tiles/wave.
// Q computed from xt in-kernel; epilogue residual from xt (L1-hot);
// f0 written with 16B vector stores.
// ---------------------------------------------------------------------------
__global__ __launch_bounds__(256, 4) void attn_kernel(
    const ushort_t* __restrict__ xt, const ushort_t* __restrict__ kg,
    const ushort_t* __restrict__ vt,
    const float* __restrict__ Wq, const float* __restrict__ bq,
    const float* __restrict__ Wo, const float* __restrict__ bo,
    const float* __restrict__ gamma_p, ushort_t* __restrict__ f0)
{
  __shared__ __attribute__((aligned(16))) ushort_t qt[4][16 * 40];
  __shared__ __attribute__((aligned(16))) ushort_t pt[4][16 * 136];
  __shared__ __attribute__((aligned(16))) ushort_t ot[4][16 * 40];
  __shared__ __attribute__((aligned(16))) ushort_t ft[4][16 * 72];

  const int bid = blockIdx.x;
  const int cell = bid >> 2;
  const int part = bid & 3;
  const int tid = threadIdx.x, lane = tid & 63, wv = tid >> 6;
  const int quad = lane >> 4, l15 = lane & 15;

  const int n  = cell >> 6;
  const int gh = (cell >> 3) & 7;
  const int gw = cell & 7;
  const int y0 = gh * 32, xc0 = gw * 32;

  const ushort_t* xtn = xt + (size_t)n * (65536 * 64);
  ushort_t*       f0n = f0 + (size_t)n * (65536 * 64);
  const ushort_t* kc  = kg + (size_t)(cell << 8) * 32;
  const ushort_t* vc  = vt + (size_t)(cell << 13);

  const float gamma = gamma_p[0];

  // Wq B-frags (64->32), Wo B-frags (32->64)
  s16x8 wqf[2][2];
#pragma unroll
  for (int ks = 0; ks < 2; ++ks)
#pragma unroll
    for (int nt = 0; nt < 2; ++nt) {
      const float* p = Wq + (nt * 16 + l15) * 64 + ks * 32 + quad * 8;
      s16x8 t;
#pragma unroll
      for (int j = 0; j < 8; ++j) t[j] = (short)f2bf(p[j]);
      wqf[ks][nt] = t;
    }
  s16x8 wof[4];
#pragma unroll
  for (int nt = 0; nt < 4; ++nt) {
    const float* p = Wo + (nt * 16 + l15) * 32 + quad * 8;
    s16x8 t;
#pragma unroll
    for (int j = 0; j < 8; ++j) t[j] = (short)f2bf(p[j]);
    wof[nt] = t;
  }
  float bqv[2]; bqv[0] = bq[l15]; bqv[1] = bq[16 + l15];
  float bov[4];
#pragma unroll
  for (int nt = 0; nt < 4; ++nt) bov[nt] = bo[nt * 16 + l15];

  ushort_t* qtw = qt[wv];
  ushort_t* ptw = pt[wv];
  ushort_t* otw = ot[wv];
  ushort_t* ftw = ft[wv];
  const f32x4 zf = {0.f, 0.f, 0.f, 0.f};

#pragma unroll 1
  for (int it = 0; it < 4; ++it) {
    const int mt = part * 16 + wv * 4 + it;   // 0..63
    const int pbase = mt * 16;

    // lane's pixel (shared by Q-gen A-frag row and epilogue)
    const int p = pbase + l15;
    const int yy = p >> 5, xx = p & 31;
    const size_t pixg = (size_t)((y0 + yy) * 256 + xc0 + xx);

    // ---- Q-gen from xt (A-frags are direct vector loads)
    const s16x8 a0 = *(const s16x8*)(xtn + pixg * 64 + quad * 8);
    const s16x8 a1 = *(const s16x8*)(xtn + pixg * 64 + 32 + quad * 8);
    f32x4 qd0 = zf, qd1 = zf;
    qd0 = __builtin_amdgcn_mfma_f32_16x16x32_bf16(a0, wqf[0][0], qd0, 0, 0, 0);
    qd0 = __builtin_amdgcn_mfma_f32_16x16x32_bf16(a1, wqf[1][0], qd0, 0, 0, 0);
    qd1 = __builtin_amdgcn_mfma_f32_16x16x32_bf16(a0, wqf[0][1], qd1, 0, 0, 0);
    qd1 = __builtin_amdgcn_mfma_f32_16x16x32_bf16(a1, wqf[1][1], qd1, 0, 0, 0);
#pragma unroll
    for (int i = 0; i < 4; ++i) {
      qtw[(quad * 4 + i) * 40 + l15]      = f2bf(qd0[i] + bqv[0]);
      qtw[(quad * 4 + i) * 40 + 16 + l15] = f2bf(qd1[i] + bqv[1]);
    }
    const s16x8 qa = *(const s16x8*)&qtw[l15 * 40 + quad * 8];

    // ---- S = Q.K^T, 16 N-tiles; K B-frags from global [kpos][32]
    f32x4 S[16];
#pragma unroll
    for (int nt = 0; nt < 16; ++nt) {
      const s16x8 kb = *(const s16x8*)(kc + (size_t)(nt * 16 + l15) * 32 + quad * 8);
      S[nt] = __builtin_amdgcn_mfma_f32_16x16x32_bf16(qa, kb, zf, 0, 0, 0);
    }

    // ---- softmax over 256 cols
    float rl[4];
#pragma unroll
    for (int i = 0; i < 4; ++i) {
      float m = S[0][i];
#pragma unroll
      for (int nt = 1; nt < 16; ++nt) m = fmaxf(m, S[nt][i]);
#pragma unroll
      for (int d2 = 1; d2 < 16; d2 <<= 1) m = fmaxf(m, __shfl_xor(m, d2, 64));
      float s = 0.f;
#pragma unroll
      for (int nt = 0; nt < 16; ++nt) {
        float e = __expf(S[nt][i] - m);
        S[nt][i] = e;
        s += e;
      }
#pragma unroll
      for (int d2 = 1; d2 < 16; d2 <<= 1) s += __shfl_xor(s, d2, 64);
      rl[i] = s;
    }

    // ---- O = P.V^T over 2 halves of 128 kpos
    f32x4 O0 = zf, O1 = zf;
#pragma unroll
    for (int hh = 0; hh < 2; ++hh) {
#pragma unroll
      for (int t = 0; t < 8; ++t)
#pragma unroll
        for (int i = 0; i < 4; ++i)
          ptw[(quad * 4 + i) * 136 + t * 16 + l15] = f2bf(S[hh * 8 + t][i]);
#pragma unroll
      for (int kk = 0; kk < 4; ++kk) {
        const s16x8 pa = *(const s16x8*)&ptw[l15 * 136 + kk * 32 + quad * 8];
        const int kb0 = hh * 128 + kk * 32 + quad * 8;
        const s16x8 vb0 = *(const s16x8*)(vc + (size_t)l15 * 256 + kb0);
        const s16x8 vb1 = *(const s16x8*)(vc + (size_t)(16 + l15) * 256 + kb0);
        O0 = __builtin_amdgcn_mfma_f32_16x16x32_bf16(pa, vb0, O0, 0, 0, 0);
        O1 = __builtin_amdgcn_mfma_f32_16x16x32_bf16(pa, vb1, O1, 0, 0, 0);
      }
    }

    // ---- normalize, C->A via LDS, project Wo -> ft tile [q][64ch]
#pragma unroll
    for (int i = 0; i < 4; ++i) {
      const float inv = 1.0f / rl[i];
      otw[(quad * 4 + i) * 40 + l15]      = f2bf(O0[i] * inv);
      otw[(quad * 4 + i) * 40 + 16 + l15] = f2bf(O1[i] * inv);
    }
    const s16x8 oa = *(const s16x8*)&otw[l15 * 40 + quad * 8];
#pragma unroll
    for (int nt = 0; nt < 4; ++nt) {
      f32x4 D = __builtin_amdgcn_mfma_f32_16x16x32_bf16(oa, wof[nt], zf, 0, 0, 0);
#pragma unroll
      for (int i = 0; i < 4; ++i)
        ftw[(quad * 4 + i) * 72 + nt * 16 + l15] = f2bf(gamma * (D[i] + bov[nt]));
    }

    // ---- epilogue: lane owns pixel l15, ch chunk quad*16..+15; +xt residual
    {
      const s16x8 fv0 = *(const s16x8*)&ftw[l15 * 72 + quad * 16];
      const s16x8 fv1 = *(const s16x8*)&ftw[l15 * 72 + quad * 16 + 8];
      const s16x8 xv0 = *(const s16x8*)(xtn + pixg * 64 + quad * 16);
      const s16x8 xv1 = *(const s16x8*)(xtn + pixg * 64 + quad * 16 + 8);
      s16x8 r0, r1;
#pragma unroll
      for (int j = 0; j < 8; ++j) {
        r0[j] = (short)f2bf(bf2f((unsigned short)fv0[j]) + bf2f((unsigned short)xv0[j]));
        r1[j] = (short)f2bf(bf2f((unsigned short)fv1[j]) + bf2f((unsigned short)xv1[j]));
      }
      *(s16x8*)(f0n + pixg * 64 + quad * 16)     = r0;
      *(s16x8*)(f0n + pixg * 64 + quad * 16 + 8) = r1;
    }
  }
}

// ---------------------------------------------------------------------------
// conv3x3 + ReLU via bf16 MFMA implicit GEMM (unchanged).
// ---------------------------------------------------------------------------
template <int NCHUNK>
__global__ __launch_bounds__(256) void conv3_kernel(
    const ushort_t* __restrict__ s0, const ushort_t* __restrict__ s1,
    const ushort_t* __restrict__ s2, const ushort_t* __restrict__ wc,
    const float* __restrict__ bias, ushort_t* __restrict__ outp)
{
  __shared__ __attribute__((aligned(16))) ushort_t tile[612 * 40];

  const int bid = blockIdx.x;
  const int n = bid >> 7;
  const int t = bid & 127;
  const int ty0 = (t >> 3) * 16;
  const int tx0 = (t & 7) * 32;
  const int tid = threadIdx.x, lane = tid & 63, wv = tid >> 6;
  const int quad = lane >> 4, l15 = lane & 15;
  constexpr int Kg = NCHUNK * 4;

  const f32x4 zf = {0.f, 0.f, 0.f, 0.f};
  f32x4 acc[4][2][2];
#pragma unroll
  for (int r = 0; r < 4; ++r)
#pragma unroll
    for (int h = 0; h < 2; ++h) { acc[r][h][0] = zf; acc[r][h][1] = zf; }

  for (int ch = 0; ch < NCHUNK; ++ch) {
    const ushort_t* src; int cstr, cbase;
    if (ch < 2)       { src = s0 + (size_t)n * (65536 * 64); cstr = 64; cbase = ch * 32; }
    else if (ch == 2) { src = s1 + (size_t)n * (65536 * 32); cstr = 32; cbase = 0; }
    else              { src = s2 + (size_t)n * (65536 * 32); cstr = 32; cbase = 0; }

    __syncthreads();
    for (int u = tid; u < 2448; u += 256) {
      const int pix = u >> 2, cg = u & 3;
      const int lr = pix / 34, lc = pix - lr * 34;
      const int gy = ty0 - 1 + lr, gx = tx0 - 1 + lc;
      s16x8 v = {0, 0, 0, 0, 0, 0, 0, 0};
      if ((unsigned)gy < 256u && (unsigned)gx < 256u)
        v = *(const s16x8*)(src + (size_t)(gy * 256 + gx) * cstr + cbase + cg * 8);
      *(s16x8*)&tile[pix * 40 + cg * 8] = v;
    }
    __syncthreads();

#pragma unroll
    for (int tap = 0; tap < 9; ++tap) {
      const int ky = tap / 3, kx = tap - ky * 3;
      const ushort_t* wb = wc + ((size_t)(tap * Kg + ch * 4 + quad) * 32 + l15) * 8;
      const s16x8 b0 = *(const s16x8*)wb;
      const s16x8 b1 = *(const s16x8*)(wb + 128);
#pragma unroll
      for (int r = 0; r < 4; ++r) {
        const int lr = 4 * wv + r + ky;
#pragma unroll
        for (int h = 0; h < 2; ++h) {
          const int lc = h * 16 + l15 + kx;
          const s16x8 a = *(const s16x8*)&tile[(lr * 34 + lc) * 40 + quad * 8];
          acc[r][h][0] = __builtin_amdgcn_mfma_f32_16x16x32_bf16(a, b0, acc[r][h][0], 0, 0, 0);
          acc[r][h][1] = __builtin_amdgcn_mfma_f32_16x16x32_bf16(a, b1, acc[r][h][1], 0, 0, 0);
        }
      }
    }
  }

  const float bv0 = bias[l15], bv1 = bias[16 + l15];
  ushort_t* on = outp + (size_t)n * (65536 * 32);
#pragma unroll
  for (int r = 0; r < 4; ++r) {
    const int gy = ty0 + 4 * wv + r;
#pragma unroll
    for (int h = 0; h < 2; ++h) {
#pragma unroll
      for (int i = 0; i < 4; ++i) {
        const int gx = tx0 + h * 16 + quad * 4 + i;
        ushort_t* op = on + (size_t)(gy * 256 + gx) * 32;
        op[l15]      = f2bf(fmaxf(acc[r][h][0][i] + bv0, 0.f));
        op[16 + l15] = f2bf(fmaxf(acc[r][h][1][i] + bv1, 0.f));
      }
    }
  }
}

// ---------------------------------------------------------------------------
// fuse: out = cat(f0..f3)[160] x Wf^T + bf + x (unchanged).
// ---------------------------------------------------------------------------
__global__ __launch_bounds__(256) void fuse_kernel(
    const ushort_t* __restrict__ f0, const ushort_t* __restrict__ f1,
    const ushort_t* __restrict__ f2, const ushort_t* __restrict__ f3,
    const float* __restrict__ x, const ushort_t* __restrict__ wff,
    const float* __restrict__ bfv, float* __restrict__ out)
{
  __shared__ float tr[4][64 * 17];

  const int tid = threadIdx.x, lane = tid & 63, wv = tid >> 6;
  const int quad = lane >> 4, l15 = lane & 15;

  s16x8 wf[5][4];
#pragma unroll
  for (int ks = 0; ks < 5; ++ks)
#pragma unroll
    for (int nt = 0; nt < 4; ++nt)
      wf[ks][nt] = *(const s16x8*)(wff + ((size_t)((ks * 4 + quad) * 64) + nt * 16 + l15) * 8);
  float bb[4];
#pragma unroll
  for (int nt = 0; nt < 4; ++nt) bb[nt] = bfv[nt * 16 + l15];

  const int wt = blockIdx.x * 4 + wv;
  const f32x4 zf = {0.f, 0.f, 0.f, 0.f};
  float* trw = tr[wv];

  for (int mt = 0; mt < 4; ++mt) {
    const int p0 = wt * 64 + mt * 16;
    const size_t pA = (size_t)(p0 + l15);
    const s16x8 a0 = *(const s16x8*)(f0 + pA * 64 + quad * 8);
    const s16x8 a1 = *(const s16x8*)(f0 + pA * 64 + 32 + quad * 8);
    const s16x8 a2 = *(const s16x8*)(f1 + pA * 32 + quad * 8);
    const s16x8 a3 = *(const s16x8*)(f2 + pA * 32 + quad * 8);
    const s16x8 a4 = *(const s16x8*)(f3 + pA * 32 + quad * 8);

    f32x4 acc[4];
#pragma unroll
    for (int nt = 0; nt < 4; ++nt) {
      f32x4 d = zf;
      d = __builtin_amdgcn_mfma_f32_16x16x32_bf16(a0, wf[0][nt], d, 0, 0, 0);
      d = __builtin_amdgcn_mfma_f32_16x16x32_bf16(a1, wf[1][nt], d, 0, 0, 0);
      d = __builtin_amdgcn_mfma_f32_16x16x32_bf16(a2, wf[2][nt], d, 0, 0, 0);
      d = __builtin_amdgcn_mfma_f32_16x16x32_bf16(a3, wf[3][nt], d, 0, 0, 0);
      d = __builtin_amdgcn_mfma_f32_16x16x32_bf16(a4, wf[4][nt], d, 0, 0, 0);
      acc[nt] = d;
    }

#pragma unroll
    for (int nt = 0; nt < 4; ++nt)
#pragma unroll
      for (int i = 0; i < 4; ++i)
        trw[(nt * 16 + l15) * 17 + quad * 4 + i] = acc[nt][i] + bb[nt];

    const int n = p0 >> 16;
    const int pix0 = p0 & 65535;
    const float* xb = x + (size_t)n * (64 * 65536);
    float* ob = out + (size_t)n * (64 * 65536);
#pragma unroll
    for (int og = 0; og < 16; ++og) {
      const int o = og * 4 + quad;
      const float v = trw[o * 17 + l15];
      const size_t g = (size_t)o * 65536 + pix0 + l15;
      ob[g] = v + xb[g];
    }
  }
}

// ---------------------------------------------------------------------------
extern "C" void kernel_launch(void* const* d_in, const int* in_sizes, int n_in,
                              void* d_out, int out_size, void* d_ws, size_t ws_size,
                              hipStream_t stream)
{
  const float* x     = (const float*)d_in[0];
  const float* Wq    = (const float*)d_in[1];
  const float* bq    = (const float*)d_in[2];
  const float* Wk    = (const float*)d_in[3];
  const float* bk    = (const float*)d_in[4];
  const float* Wv    = (const float*)d_in[5];
  const float* bv    = (const float*)d_in[6];
  const float* Wo    = (const float*)d_in[7];
  const float* bo    = (const float*)d_in[8];
  const float* gamma = (const float*)d_in[9];
  const float* W1    = (const float*)d_in[10];
  const float* b1    = (const float*)d_in[11];
  const float* W2    = (const float*)d_in[12];
  const float* b2    = (const float*)d_in[13];
  const float* W3    = (const float*)d_in[14];
  const float* b3    = (const float*)d_in[15];
  const float* Wf    = (const float*)d_in[16];
  const float* bf    = (const float*)d_in[17];

  float* out = (float*)d_out;
  ushort_t* wsu = (ushort_t*)d_ws;

  // bf16 feature buffers, pixel-major [n][y][x][c]
  ushort_t* f0 = wsu;                       // 16,777,216
  ushort_t* f1 = wsu + 16777216;            //  8,388,608
  ushort_t* f2 = wsu + 25165824;            //  8,388,608
  ushort_t* f3 = wsu + 33554432;            //  8,388,608
  // xt overlays f1+f2 (dead before conv1 writes f1);
  // kg/vt overlay f3 (dead before conv3 writes f3)
  ushort_t* xtb = wsu + 16777216;           // 16,777,216
  ushort_t* kgb = wsu + 33554432;           //  2,097,152
  ushort_t* vtb = wsu + 35651584;           //  2,097,152
  ushort_t* wc1 = wsu + 41943040;           // 18432
  ushort_t* wc2 = wc1 + 18432;              // 27648
  ushort_t* wc3 = wc2 + 27648;              // 36864
  ushort_t* wff = wc3 + 36864;              // 10240

  repack_kernel<<<144, 256, 0, stream>>>(W1, W2, W3, Wf, wc1, wc2, wc3, wff);
  kvx_kernel<<<2048, 256, 0, stream>>>(x, Wk, bk, Wv, bv, xtb, kgb, vtb);
  attn_kernel<<<1024, 256, 0, stream>>>(xtb, kgb, vtb, Wq, bq, Wo, bo, gamma, f0);
  conv3_kernel<2><<<512, 256, 0, stream>>>(f0, f1, f2, wc1, b1, f1);
  conv3_kernel<3><<<512, 256, 0, stream>>>(f0, f1, f2, wc2, b2, f2);
  conv3_kernel<4><<<512, 256, 0, stream>>>(f0, f1, f2, wc3, b3, f3);
  fuse_kernel<<<1024, 256, 0, stream>>>(f0, f1, f2, f3, x, wff, bf, out);
}

// Round 5
// 345.609 us; speedup vs baseline: 1.3515x; 1.3515x over previous
//
#include <hip/hip_runtime.h>

// ============================================================================
// RegionNonLocalEnhancedDenseBlock on MI355X (gfx950) — Round 5
//  - kvx_kernel: x -> xt (bf16 pixel-major) + pooled K / V^T (unchanged).
//  - attn_kernel: K/V staged to LDS ONCE per block (kills the 512MB logical
//    K/V re-read that thrashed L2 in r3/r4); per-wave scratch unioned into
//    one buffer (52.5 KB LDS total -> 3 blocks/CU).
//  - conv3x3 / fuse unchanged (bf16 MFMA implicit GEMM).
// ============================================================================

typedef short s16x8 __attribute__((ext_vector_type(8)));
typedef float f32x4 __attribute__((ext_vector_type(4)));
typedef unsigned short ushort_t;

__device__ __forceinline__ unsigned short f2bf(float f) {
  union { float f; unsigned int u; } v; v.f = f;
  unsigned int r = v.u + 0x7fffu + ((v.u >> 16) & 1u);  // RNE
  return (unsigned short)(r >> 16);
}
__device__ __forceinline__ float bf2f(unsigned short h) {
  union { unsigned int u; float f; } v; v.u = ((unsigned int)h) << 16;
  return v.f;
}

// ---------------------------------------------------------------------------
// Repack conv/fuse weights -> bf16 MFMA B-frag order.
// ---------------------------------------------------------------------------
__global__ void repack_kernel(const float* __restrict__ W1, const float* __restrict__ W2,
                              const float* __restrict__ W3, const float* __restrict__ Wf,
                              ushort_t* __restrict__ wc1, ushort_t* __restrict__ wc2,
                              ushort_t* __restrict__ wc3, ushort_t* __restrict__ wff)
{
  const int i = blockIdx.x * 256 + threadIdx.x;
  if (i < 18432) {  // W1 [32][64][3][3], Kg=8
    int j = i & 7, o = (i >> 3) & 31, r = i >> 8, tap = r >> 3, kg = r & 7;
    wc1[i] = f2bf(W1[o * 576 + (kg * 8 + j) * 9 + tap]);
  }
  if (i < 27648) {  // W2 [32][96][3][3], Kg=12
    int j = i & 7, o = (i >> 3) & 31, r = i >> 8, tap = r / 12, kg = r % 12;
    wc2[i] = f2bf(W2[o * 864 + (kg * 8 + j) * 9 + tap]);
  }
  if (i < 36864) {  // W3 [32][128][3][3], Kg=16
    int j = i & 7, o = (i >> 3) & 31, r = i >> 8, tap = r >> 4, kg = r & 15;
    wc3[i] = f2bf(W3[o * 1152 + (kg * 8 + j) * 9 + tap]);
  }
  if (i < 10240) {  // Wf [64][160], Kg=20
    int j = i & 7, o = (i >> 3) & 63, kg = i >> 9;
    wff[i] = f2bf(Wf[o * 160 + kg * 8 + j]);
  }
}

// ---------------------------------------------------------------------------
// kvx_kernel: grid 2048 (8 blocks/cell, 4 waves). Wave w=0..31 of a cell:
// rows {2yp, 2yp+1}, x-half h. Emits xt (bf16 pixel-major), pooled K, V^T.
// ---------------------------------------------------------------------------
__global__ __launch_bounds__(256, 4) void kvx_kernel(
    const float* __restrict__ x,
    const float* __restrict__ Wk, const float* __restrict__ bk,
    const float* __restrict__ Wv, const float* __restrict__ bv,
    ushort_t* __restrict__ xt, ushort_t* __restrict__ kg, ushort_t* __restrict__ vt)
{
  __shared__ ushort_t kvs[4][8][64];  // [wave][kpos_local][K 0..31 | V 32..63]

  const int bid = blockIdx.x;
  const int cell = bid >> 3;
  const int tid = threadIdx.x, lane = tid & 63, wv = tid >> 6;
  const int w = (bid & 7) * 4 + wv;        // 0..31 within cell
  const int yp = w >> 1, h = w & 1;
  const int quad = lane >> 4, l15 = lane & 15;

  const int n  = cell >> 6;
  const int gh = (cell >> 3) & 7;
  const int gw = cell & 7;
  const int y0 = gh * 32, xc0 = gw * 32;
  const float* xn  = x  + (size_t)n * (64 * 65536);
  ushort_t*    xtn = xt + (size_t)n * (65536 * 64);

  s16x8 wkf[2][2], wvf[2][2];
#pragma unroll
  for (int ks = 0; ks < 2; ++ks)
#pragma unroll
    for (int nt = 0; nt < 2; ++nt) {
      const int off = (nt * 16 + l15) * 64 + ks * 32 + quad * 8;
      s16x8 tk, tv;
#pragma unroll
      for (int j = 0; j < 8; ++j) {
        tk[j] = (short)f2bf(Wk[off + j]);
        tv[j] = (short)f2bf(Wv[off + j]);
      }
      wkf[ks][nt] = tk; wvf[ks][nt] = tv;
    }
  float bkv[2], bvv[2];
#pragma unroll
  for (int nt = 0; nt < 2; ++nt) {
    bkv[nt] = bk[nt * 16 + l15];
    bvv[nt] = bv[nt * 16 + l15];
  }

  const f32x4 zf = {0.f, 0.f, 0.f, 0.f};
  f32x4 kd[2][2], vd[2][2];

#pragma unroll
  for (int t2 = 0; t2 < 2; ++t2) {
    const int yy = 2 * yp + t2;
    const int xx = h * 16 + l15;
    const float* px = xn + (y0 + yy) * 256 + xc0 + xx;

    s16x8 a[2];
#pragma unroll
    for (int ks = 0; ks < 2; ++ks)
#pragma unroll
      for (int j = 0; j < 8; ++j)
        a[ks][j] = (short)f2bf(px[(size_t)(ks * 32 + quad * 8 + j) * 65536]);

    const size_t pixg = (size_t)((y0 + yy) * 256 + xc0 + xx);
    *(s16x8*)(xtn + pixg * 64 + quad * 8)      = a[0];
    *(s16x8*)(xtn + pixg * 64 + 32 + quad * 8) = a[1];

#pragma unroll
    for (int nt = 0; nt < 2; ++nt) {
      kd[t2][nt] = zf; vd[t2][nt] = zf;
#pragma unroll
      for (int ks = 0; ks < 2; ++ks) {
        kd[t2][nt] = __builtin_amdgcn_mfma_f32_16x16x32_bf16(a[ks], wkf[ks][nt], kd[t2][nt], 0, 0, 0);
        vd[t2][nt] = __builtin_amdgcn_mfma_f32_16x16x32_bf16(a[ks], wvf[ks][nt], vd[t2][nt], 0, 0, 0);
      }
    }
  }

#pragma unroll
  for (int nt = 0; nt < 2; ++nt) {
#pragma unroll
    for (int r = 0; r < 2; ++r) {
      const float kp = fmaxf(fmaxf(kd[0][nt][2 * r], kd[0][nt][2 * r + 1]),
                             fmaxf(kd[1][nt][2 * r], kd[1][nt][2 * r + 1])) + bkv[nt];
      const float vp = fmaxf(fmaxf(vd[0][nt][2 * r], vd[0][nt][2 * r + 1]),
                             fmaxf(vd[1][nt][2 * r], vd[1][nt][2 * r + 1])) + bvv[nt];
      kvs[wv][quad * 2 + r][nt * 16 + l15]      = f2bf(kp);
      kvs[wv][quad * 2 + r][32 + nt * 16 + l15] = f2bf(vp);
    }
  }
  __syncthreads();

  const int kpos0 = yp * 16 + h * 8;   // wave's 8 contiguous kpos
  if (lane < 32) {
    const s16x8 vv = *(const s16x8*)&kvs[wv][lane >> 2][(lane & 3) * 8];
    *(s16x8*)(kg + ((size_t)(cell << 8) + kpos0 + (lane >> 2)) * 32 + (lane & 3) * 8) = vv;
  } else {
    const int ch = lane - 32;
    s16x8 vv;
#pragma unroll
    for (int r = 0; r < 8; ++r) vv[r] = (short)kvs[wv][r][32 + ch];
    *(s16x8*)(vt + (size_t)(cell << 13) + ch * 256 + kpos0) = vv;
  }
}

// ---------------------------------------------------------------------------
// attn_kernel: grid 1024 (4 blocks/cell), 4 waves, 4 M-tiles/wave.
// K/V staged into LDS once per block; per-wave scratch unioned (sequential
// lifetimes: qt -> pt -> ot -> ft, wave-private so no barrier needed).
// ---------------------------------------------------------------------------
__global__ __launch_bounds__(256, 3) void attn_kernel(
    const ushort_t* __restrict__ xt, const ushort_t* __restrict__ kg,
    const ushort_t* __restrict__ vt,
    const float* __restrict__ Wq, const float* __restrict__ bq,
    const float* __restrict__ Wo, const float* __restrict__ bo,
    const float* __restrict__ gamma_p, ushort_t* __restrict__ f0)
{
  __shared__ __attribute__((aligned(16))) ushort_t kl[256 * 36];  // K [kpos][32] pad36
  __shared__ __attribute__((aligned(16))) ushort_t vl[32 * 260];  // V^T [ch][256] pad260
  __shared__ __attribute__((aligned(16))) ushort_t un[4][2176];   // per-wave scratch

  const int bid = blockIdx.x;
  const int cell = bid >> 2;
  const int part = bid & 3;
  const int tid = threadIdx.x, lane = tid & 63, wv = tid >> 6;
  const int quad = lane >> 4, l15 = lane & 15;

  const int n  = cell >> 6;
  const int gh = (cell >> 3) & 7;
  const int gw = cell & 7;
  const int y0 = gh * 32, xc0 = gw * 32;

  const ushort_t* xtn = xt + (size_t)n * (65536 * 64);
  ushort_t*       f0n = f0 + (size_t)n * (65536 * 64);
  const ushort_t* kc  = kg + (size_t)(cell << 8) * 32;
  const ushort_t* vc  = vt + (size_t)(cell << 13);

  // ---- stage K and V^T into LDS (one pass, b128 both sides)
  for (int idx = tid; idx < 1024; idx += 256) {
    const int kpos = idx >> 2, cg = idx & 3;
    *(s16x8*)&kl[kpos * 36 + cg * 8] = *(const s16x8*)(kc + kpos * 32 + cg * 8);
  }
  for (int idx = tid; idx < 1024; idx += 256) {
    const int ch = idx >> 5, seg = idx & 31;
    *(s16x8*)&vl[ch * 260 + seg * 8] = *(const s16x8*)(vc + ch * 256 + seg * 8);
  }

  const float gamma = gamma_p[0];

  s16x8 wqf[2][2];
#pragma unroll
  for (int ks = 0; ks < 2; ++ks)
#pragma unroll
    for (int nt = 0; nt < 2; ++nt) {
      const float* p = Wq + (nt * 16 + l15) * 64 + ks * 32 + quad * 8;
      s16x8 t;
#pragma unroll
      for (int j = 0; j < 8; ++j) t[j] = (short)f2bf(p[j]);
      wqf[ks][nt] = t;
    }
  s16x8 wof[4];
#pragma unroll
  for (int nt = 0; nt < 4; ++nt) {
    const float* p = Wo + (nt * 16 + l15) * 32 + quad * 8;
    s16x8 t;
#pragma unroll
    for (int j = 0; j < 8; ++j) t[j] = (short)f2bf(p[j]);
    wof[nt] = t;
  }
  float bqv[2]; bqv[0] = bq[l15]; bqv[1] = bq[16 + l15];
  float bov[4];
#pragma unroll
  for (int nt = 0; nt < 4; ++nt) bov[nt] = bo[nt * 16 + l15];

  __syncthreads();   // K/V staged

  ushort_t* uw = un[wv];
  const f32x4 zf = {0.f, 0.f, 0.f, 0.f};

#pragma unroll 1
  for (int it = 0; it < 4; ++it) {
    const int mt = part * 16 + wv * 4 + it;   // 0..63
    const int pbase = mt * 16;

    const int p = pbase + l15;
    const int yy = p >> 5, xx = p & 31;
    const size_t pixg = (size_t)((y0 + yy) * 256 + xc0 + xx);

    // ---- Q-gen from xt
    const s16x8 a0 = *(const s16x8*)(xtn + pixg * 64 + quad * 8);
    const s16x8 a1 = *(const s16x8*)(xtn + pixg * 64 + 32 + quad * 8);
    f32x4 qd0 = zf, qd1 = zf;
    qd0 = __builtin_amdgcn_mfma_f32_16x16x32_bf16(a0, wqf[0][0], qd0, 0, 0, 0);
    qd0 = __builtin_amdgcn_mfma_f32_16x16x32_bf16(a1, wqf[1][0], qd0, 0, 0, 0);
    qd1 = __builtin_amdgcn_mfma_f32_16x16x32_bf16(a0, wqf[0][1], qd1, 0, 0, 0);
    qd1 = __builtin_amdgcn_mfma_f32_16x16x32_bf16(a1, wqf[1][1], qd1, 0, 0, 0);
    // qt phase of union buffer (stride 40)
#pragma unroll
    for (int i = 0; i < 4; ++i) {
      uw[(quad * 4 + i) * 40 + l15]      = f2bf(qd0[i] + bqv[0]);
      uw[(quad * 4 + i) * 40 + 16 + l15] = f2bf(qd1[i] + bqv[1]);
    }
    const s16x8 qa = *(const s16x8*)&uw[l15 * 40 + quad * 8];

    // ---- S = Q.K^T, 16 N-tiles; K B-frags from LDS
    f32x4 S[16];
#pragma unroll
    for (int nt = 0; nt < 16; ++nt) {
      const s16x8 kb = *(const s16x8*)&kl[(nt * 16 + l15) * 36 + quad * 8];
      S[nt] = __builtin_amdgcn_mfma_f32_16x16x32_bf16(qa, kb, zf, 0, 0, 0);
    }

    // ---- softmax over 256 cols
    float rl[4];
#pragma unroll
    for (int i = 0; i < 4; ++i) {
      float m = S[0][i];
#pragma unroll
      for (int nt = 1; nt < 16; ++nt) m = fmaxf(m, S[nt][i]);
#pragma unroll
      for (int d2 = 1; d2 < 16; d2 <<= 1) m = fmaxf(m, __shfl_xor(m, d2, 64));
      float s = 0.f;
#pragma unroll
      for (int nt = 0; nt < 16; ++nt) {
        float e = __expf(S[nt][i] - m);
        S[nt][i] = e;
        s += e;
      }
#pragma unroll
      for (int d2 = 1; d2 < 16; d2 <<= 1) s += __shfl_xor(s, d2, 64);
      rl[i] = s;
    }

    // ---- O = P.V^T over 2 halves of 128 kpos (pt phase, stride 136)
    f32x4 O0 = zf, O1 = zf;
#pragma unroll
    for (int hh = 0; hh < 2; ++hh) {
#pragma unroll
      for (int t = 0; t < 8; ++t)
#pragma unroll
        for (int i = 0; i < 4; ++i)
          uw[(quad * 4 + i) * 136 + t * 16 + l15] = f2bf(S[hh * 8 + t][i]);
#pragma unroll
      for (int kk = 0; kk < 4; ++kk) {
        const s16x8 pa = *(const s16x8*)&uw[l15 * 136 + kk * 32 + quad * 8];
        const int kb0 = hh * 128 + kk * 32 + quad * 8;
        const s16x8 vb0 = *(const s16x8*)&vl[l15 * 260 + kb0];
        const s16x8 vb1 = *(const s16x8*)&vl[(16 + l15) * 260 + kb0];
        O0 = __builtin_amdgcn_mfma_f32_16x16x32_bf16(pa, vb0, O0, 0, 0, 0);
        O1 = __builtin_amdgcn_mfma_f32_16x16x32_bf16(pa, vb1, O1, 0, 0, 0);
      }
    }

    // ---- normalize, C->A (ot phase, stride 40), project Wo
#pragma unroll
    for (int i = 0; i < 4; ++i) {
      const float inv = 1.0f / rl[i];
      uw[(quad * 4 + i) * 40 + l15]      = f2bf(O0[i] * inv);
      uw[(quad * 4 + i) * 40 + 16 + l15] = f2bf(O1[i] * inv);
    }
    const s16x8 oa = *(const s16x8*)&uw[l15 * 40 + quad * 8];
    // ft phase (stride 72): [q][64ch]
#pragma unroll
    for (int nt = 0; nt < 4; ++nt) {
      f32x4 D = __builtin_amdgcn_mfma_f32_16x16x32_bf16(oa, wof[nt], zf, 0, 0, 0);
#pragma unroll
      for (int i = 0; i < 4; ++i)
        uw[(quad * 4 + i) * 72 + nt * 16 + l15] = f2bf(gamma * (D[i] + bov[nt]));
    }

    // ---- epilogue: +xt residual, 16B vector stores
    {
      const s16x8 fv0 = *(const s16x8*)&uw[l15 * 72 + quad * 16];
      const s16x8 fv1 = *(const s16x8*)&uw[l15 * 72 + quad * 16 + 8];
      const s16x8 xv0 = *(const s16x8*)(xtn + pixg * 64 + quad * 16);
      const s16x8 xv1 = *(const s16x8*)(xtn + pixg * 64 + quad * 16 + 8);
      s16x8 r0, r1;
#pragma unroll
      for (int j = 0; j < 8; ++j) {
        r0[j] = (short)f2bf(bf2f((unsigned short)fv0[j]) + bf2f((unsigned short)xv0[j]));
        r1[j] = (short)f2bf(bf2f((unsigned short)fv1[j]) + bf2f((unsigned short)xv1[j]));
      }
      *(s16x8*)(f0n + pixg * 64 + quad * 16)     = r0;
      *(s16x8*)(f0n + pixg * 64 + quad * 16 + 8) = r1;
    }
  }
}

// ---------------------------------------------------------------------------
// conv3x3 + ReLU via bf16 MFMA implicit GEMM (unchanged).
// ---------------------------------------------------------------------------
template <int NCHUNK>
__global__ __launch_bounds__(256) void conv3_kernel(
    const ushort_t* __restrict__ s0, const ushort_t* __restrict__ s1,
    const ushort_t* __restrict__ s2, const ushort_t* __restrict__ wc,
    const float* __restrict__ bias, ushort_t* __restrict__ outp)
{
  __shared__ __attribute__((aligned(16))) ushort_t tile[612 * 40];

  const int bid = blockIdx.x;
  const int n = bid >> 7;
  const int t = bid & 127;
  const int ty0 = (t >> 3) * 16;
  const int tx0 = (t & 7) * 32;
  const int tid = threadIdx.x, lane = tid & 63, wv = tid >> 6;
  const int quad = lane >> 4, l15 = lane & 15;
  constexpr int Kg = NCHUNK * 4;

  const f32x4 zf = {0.f, 0.f, 0.f, 0.f};
  f32x4 acc[4][2][2];
#pragma unroll
  for (int r = 0; r < 4; ++r)
#pragma unroll
    for (int h = 0; h < 2; ++h) { acc[r][h][0] = zf; acc[r][h][1] = zf; }

  for (int ch = 0; ch < NCHUNK; ++ch) {
    const ushort_t* src; int cstr, cbase;
    if (ch < 2)       { src = s0 + (size_t)n * (65536 * 64); cstr = 64; cbase = ch * 32; }
    else if (ch == 2) { src = s1 + (size_t)n * (65536 * 32); cstr = 32; cbase = 0; }
    else              { src = s2 + (size_t)n * (65536 * 32); cstr = 32; cbase = 0; }

    __syncthreads();
    for (int u = tid; u < 2448; u += 256) {
      const int pix = u >> 2, cg = u & 3;
      const int lr = pix / 34, lc = pix - lr * 34;
      const int gy = ty0 - 1 + lr, gx = tx0 - 1 + lc;
      s16x8 v = {0, 0, 0, 0, 0, 0, 0, 0};
      if ((unsigned)gy < 256u && (unsigned)gx < 256u)
        v = *(const s16x8*)(src + (size_t)(gy * 256 + gx) * cstr + cbase + cg * 8);
      *(s16x8*)&tile[pix * 40 + cg * 8] = v;
    }
    __syncthreads();

#pragma unroll
    for (int tap = 0; tap < 9; ++tap) {
      const int ky = tap / 3, kx = tap - ky * 3;
      const ushort_t* wb = wc + ((size_t)(tap * Kg + ch * 4 + quad) * 32 + l15) * 8;
      const s16x8 b0 = *(const s16x8*)wb;
      const s16x8 b1 = *(const s16x8*)(wb + 128);
#pragma unroll
      for (int r = 0; r < 4; ++r) {
        const int lr = 4 * wv + r + ky;
#pragma unroll
        for (int h = 0; h < 2; ++h) {
          const int lc = h * 16 + l15 + kx;
          const s16x8 a = *(const s16x8*)&tile[(lr * 34 + lc) * 40 + quad * 8];
          acc[r][h][0] = __builtin_amdgcn_mfma_f32_16x16x32_bf16(a, b0, acc[r][h][0], 0, 0, 0);
          acc[r][h][1] = __builtin_amdgcn_mfma_f32_16x16x32_bf16(a, b1, acc[r][h][1], 0, 0, 0);
        }
      }
    }
  }

  const float bv0 = bias[l15], bv1 = bias[16 + l15];
  ushort_t* on = outp + (size_t)n * (65536 * 32);
#pragma unroll
  for (int r = 0; r < 4; ++r) {
    const int gy = ty0 + 4 * wv + r;
#pragma unroll
    for (int h = 0; h < 2; ++h) {
#pragma unroll
      for (int i = 0; i < 4; ++i) {
        const int gx = tx0 + h * 16 + quad * 4 + i;
        ushort_t* op = on + (size_t)(gy * 256 + gx) * 32;
        op[l15]      = f2bf(fmaxf(acc[r][h][0][i] + bv0, 0.f));
        op[16 + l15] = f2bf(fmaxf(acc[r][h][1][i] + bv1, 0.f));
      }
    }
  }
}

// ---------------------------------------------------------------------------
// fuse: out = cat(f0..f3)[160] x Wf^T + bf + x (unchanged).
// ---------------------------------------------------------------------------
__global__ __launch_bounds__(256) void fuse_kernel(
    const ushort_t* __restrict__ f0, const ushort_t* __restrict__ f1,
    const ushort_t* __restrict__ f2, const ushort_t* __restrict__ f3,
    const float* __restrict__ x, const ushort_t* __restrict__ wff,
    const float* __restrict__ bfv, float* __restrict__ out)
{
  __shared__ float tr[4][64 * 17];

  const int tid = threadIdx.x, lane = tid & 63, wv = tid >> 6;
  const int quad = lane >> 4, l15 = lane & 15;

  s16x8 wf[5][4];
#pragma unroll
  for (int ks = 0; ks < 5; ++ks)
#pragma unroll
    for (int nt = 0; nt < 4; ++nt)
      wf[ks][nt] = *(const s16x8*)(wff + ((size_t)((ks * 4 + quad) * 64) + nt * 16 + l15) * 8);
  float bb[4];
#pragma unroll
  for (int nt = 0; nt < 4; ++nt) bb[nt] = bfv[nt * 16 + l15];

  const int wt = blockIdx.x * 4 + wv;
  const f32x4 zf = {0.f, 0.f, 0.f, 0.f};
  float* trw = tr[wv];

  for (int mt = 0; mt < 4; ++mt) {
    const int p0 = wt * 64 + mt * 16;
    const size_t pA = (size_t)(p0 + l15);
    const s16x8 a0 = *(const s16x8*)(f0 + pA * 64 + quad * 8);
    const s16x8 a1 = *(const s16x8*)(f0 + pA * 64 + 32 + quad * 8);
    const s16x8 a2 = *(const s16x8*)(f1 + pA * 32 + quad * 8);
    const s16x8 a3 = *(const s16x8*)(f2 + pA * 32 + quad * 8);
    const s16x8 a4 = *(const s16x8*)(f3 + pA * 32 + quad * 8);

    f32x4 acc[4];
#pragma unroll
    for (int nt = 0; nt < 4; ++nt) {
      f32x4 d = zf;
      d = __builtin_amdgcn_mfma_f32_16x16x32_bf16(a0, wf[0][nt], d, 0, 0, 0);
      d = __builtin_amdgcn_mfma_f32_16x16x32_bf16(a1, wf[1][nt], d, 0, 0, 0);
      d = __builtin_amdgcn_mfma_f32_16x16x32_bf16(a2, wf[2][nt], d, 0, 0, 0);
      d = __builtin_amdgcn_mfma_f32_16x16x32_bf16(a3, wf[3][nt], d, 0, 0, 0);
      d = __builtin_amdgcn_mfma_f32_16x16x32_bf16(a4, wf[4][nt], d, 0, 0, 0);
      acc[nt] = d;
    }

#pragma unroll
    for (int nt = 0; nt < 4; ++nt)
#pragma unroll
      for (int i = 0; i < 4; ++i)
        trw[(nt * 16 + l15) * 17 + quad * 4 + i] = acc[nt][i] + bb[nt];

    const int n = p0 >> 16;
    const int pix0 = p0 & 65535;
    const float* xb = x + (size_t)n * (64 * 65536);
    float* ob = out + (size_t)n * (64 * 65536);
#pragma unroll
    for (int og = 0; og < 16; ++og) {
      const int o = og * 4 + quad;
      const float v = trw[o * 17 + l15];
      const size_t g = (size_t)o * 65536 + pix0 + l15;
      ob[g] = v + xb[g];
    }
  }
}

// ---------------------------------------------------------------------------
extern "C" void kernel_launch(void* const* d_in, const int* in_sizes, int n_in,
                              void* d_out, int out_size, void* d_ws, size_t ws_size,
                              hipStream_t stream)
{
  const float* x     = (const float*)d_in[0];
  const float* Wq    = (const float*)d_in[1];
  const float* bq    = (const float*)d_in[2];
  const float* Wk    = (const float*)d_in[3];
  const float* bk    = (const float*)d_in[4];
  const float* Wv    = (const float*)d_in[5];
  const float* bv    = (const float*)d_in[6];
  const float* Wo    = (const float*)d_in[7];
  const float* bo    = (const float*)d_in[8];
  const float* gamma = (const float*)d_in[9];
  const float* W1    = (const float*)d_in[10];
  const float* b1    = (const float*)d_in[11];
  const float* W2    = (const float*)d_in[12];
  const float* b2    = (const float*)d_in[13];
  const float* W3    = (const float*)d_in[14];
  const float* b3    = (const float*)d_in[15];
  const float* Wf    = (const float*)d_in[16];
  const float* bf    = (const float*)d_in[17];

  float* out = (float*)d_out;
  ushort_t* wsu = (ushort_t*)d_ws;

  // bf16 feature buffers, pixel-major [n][y][x][c]
  ushort_t* f0 = wsu;                       // 16,777,216
  ushort_t* f1 = wsu + 16777216;            //  8,388,608
  ushort_t* f2 = wsu + 25165824;            //  8,388,608
  ushort_t* f3 = wsu + 33554432;            //  8,388,608
  // xt overlays f1+f2 (dead before conv1 writes f1);
  // kg/vt overlay f3 (dead before conv3 writes f3)
  ushort_t* xtb = wsu + 16777216;           // 16,777,216
  ushort_t* kgb = wsu + 33554432;           //  2,097,152
  ushort_t* vtb = wsu + 35651584;           //  2,097,152
  ushort_t* wc1 = wsu + 41943040;           // 18432
  ushort_t* wc2 = wc1 + 18432;              // 27648
  ushort_t* wc3 = wc2 + 27648;              // 36864
  ushort_t* wff = wc3 + 36864;              // 10240

  repack_kernel<<<144, 256, 0, stream>>>(W1, W2, W3, Wf, wc1, wc2, wc3, wff);
  kvx_kernel<<<2048, 256, 0, stream>>>(x, Wk, bk, Wv, bv, xtb, kgb, vtb);
  attn_kernel<<<1024, 256, 0, stream>>>(xtb, kgb, vtb, Wq, bq, Wo, bo, gamma, f0);
  conv3_kernel<2><<<512, 256, 0, stream>>>(f0, f1, f2, wc1, b1, f1);
  conv3_kernel<3><<<512, 256, 0, stream>>>(f0, f1, f2, wc2, b2, f2);
  conv3_kernel<4><<<512, 256, 0, stream>>>(f0, f1, f2, wc3, b3, f3);
  fuse_kernel<<<1024, 256, 0, stream>>>(f0, f1, f2, f3, x, wff, bf, out);
}